// Round 8
// baseline (277.542 us; speedup 1.0000x reference)
//
#include <hip/hip_runtime.h>

#define B_SZ 1024
#define D_SZ 128
#define KTERMS 7
#define QPAD 36   // floats per quarter-segment: 32 data + 4 pad -> quarter bases 4 banks apart

typedef float vfloat4 __attribute__((ext_vector_type(4)));

__device__ inline float bflo(unsigned u) { return __uint_as_float(u << 16); }
__device__ inline float bfhi(unsigned u) { return __uint_as_float(u & 0xffff0000u); }

// 32-elem dot: 16 bf16-pair uints (REGISTERS) x 8 LDS float4 reads.
// Within a wave each read inst touches 4 distinct addresses (one per quarter),
// spaced QPAD=36 floats = 4 banks apart -> conflict-free broadcast.
__device__ inline float dot32(const unsigned* rq, const float* v) {
    float a0 = 0.f, a1 = 0.f, a2 = 0.f, a3 = 0.f;
#pragma unroll
    for (int j = 0; j < 8; ++j) {
        vfloat4 vv = *(const vfloat4*)(v + 4 * j);
        a0 = fmaf(bflo(rq[2 * j]),     vv.x, a0);
        a1 = fmaf(bfhi(rq[2 * j]),     vv.y, a1);
        a2 = fmaf(bflo(rq[2 * j + 1]), vv.z, a2);
        a3 = fmaf(bfhi(rq[2 * j + 1]), vv.w, a3);
    }
    return (a0 + a1) + (a2 + a3);
}

// One block (512 threads) per batch element; 4 blocks/CU (LDS ~2.9 KB) -> ONE generation.
// Thread tid owns quarter-row: row = tid>>2, q = tid&3, cols [32q, 32q+32) of BOTH A0 and W,
// bf16-packed in 32 uint registers (cvt_pk outputs - not rematerializable, not spillable to LDS).
// P3 per term k: Round A: partial u1 = A0q.v, u2 = Wq.v (SAME v-read for both dots),
//   combine quarters via shfl_xor(1)+shfl_xor(2); Round B: u3 = A0.u2, u4 = W.u1;
//   update wn = h*u1 + hs*u2 - c3*(u3-u4).  Matrix data touches NO memory in P3.
__global__ void __launch_bounds__(512, 4)
magnus_kernel(const float* __restrict__ t0p, const float* __restrict__ hp,
              const float* __restrict__ y0, const float* __restrict__ A0,
              const float* __restrict__ W, float* __restrict__ out)
{
    __shared__ __align__(16) float svr [4 * QPAD];
    __shared__ __align__(16) float su1r[4 * QPAD];
    __shared__ __align__(16) float su2r[4 * QPAD];
    __shared__ __align__(16) float su3r[4 * QPAD];
    __shared__ __align__(16) float su4r[4 * QPAD];

    const int b   = blockIdx.x;
    const int tid = threadIdx.x;
    const int row = tid >> 2;     // 0..127
    const int q   = tid & 3;      // quarter 0..3
    const float h  = hp[0];
    const float tb = t0p[b];
    const float SQ3_6 = 0.28867513459481287f;  // sqrt(3)/6
    const float t1 = tb + (0.5f - SQ3_6) * h;
    const float t2 = tb + (0.5f + SQ3_6) * h;

    const size_t moff = (size_t)b * (D_SZ * D_SZ);
    const int fbase = row * 32 + q * 8;    // float4 index of this thread's 128B chunk
    const float4* Ap = (const float4*)(A0 + moff) + fbase;
    const float4* Wp = (const float4*)(W + moff) + fbase;
    float4* o1 = (float4*)(out + (size_t)B_SZ * D_SZ + moff) + fbase;
    float4* o2 = (float4*)(out + (size_t)B_SZ * D_SZ
                               + (size_t)B_SZ * D_SZ * D_SZ + moff) + fbase;

    // ---- P1: stream A0,W; emit A1,A2; pack this thread's quarter-rows to bf16 regs ----
    // Lanes stride 128B per inst; each thread covers its 128B contiguously over it=0..7,
    // so every 64B line is fully read/written (L1/L2 merge partial-line accesses).
    unsigned ra[16], rw[16];
#pragma unroll
    for (int it = 0; it < 8; ++it) {
        float4 a = Ap[it];
        float4 w = Wp[it];
        float4 p1, p2;
        p1.x = fmaf(t1, w.x, a.x); p1.y = fmaf(t1, w.y, a.y);
        p1.z = fmaf(t1, w.z, a.z); p1.w = fmaf(t1, w.w, a.w);
        p2.x = fmaf(t2, w.x, a.x); p2.y = fmaf(t2, w.y, a.y);
        p2.z = fmaf(t2, w.z, a.z); p2.w = fmaf(t2, w.w, a.w);
        o1[it] = p1;
        o2[it] = p2;
        asm("v_cvt_pk_bf16_f32 %0, %1, %2" : "=v"(ra[2*it])   : "v"(a.x), "v"(a.y));
        asm("v_cvt_pk_bf16_f32 %0, %1, %2" : "=v"(ra[2*it+1]) : "v"(a.z), "v"(a.w));
        asm("v_cvt_pk_bf16_f32 %0, %1, %2" : "=v"(rw[2*it])   : "v"(w.x), "v"(w.y));
        asm("v_cvt_pk_bf16_f32 %0, %1, %2" : "=v"(rw[2*it+1]) : "v"(w.z), "v"(w.w));
    }

    // ---- P3 init ----
    float yacc = 0.0f;
    if (tid < D_SZ) {
        float v = y0[(size_t)b * D_SZ + tid];
        svr[(tid >> 5) * QPAD + (tid & 31)] = v;
        yacc = v;
    }
    __syncthreads();

    const float hs = h * (tb + 0.5f * h);           // h * s
    const float c3 = h * h * h * (1.0f / 12.0f);    // h^3 / 12
    const int uflat = (row >> 5) * QPAD + (row & 31);   // this row's slot in u-arrays
    // KTERMS=7: ||Omega|| <~ 0.3 -> truncation ~0.3^8/8! ~ 2e-8, invisible vs bf16 noise.

#pragma unroll
    for (int k = 1; k <= KTERMS; ++k) {
        // Round A: u1 = A0 v, u2 = W v (both dots share one v-read)
        {
            const float* vq = svr + q * QPAD;
            float pa = dot32(ra, vq);
            float pw = dot32(rw, vq);
            pa += __shfl_xor(pa, 1); pa += __shfl_xor(pa, 2);
            pw += __shfl_xor(pw, 1); pw += __shfl_xor(pw, 2);
            if (q == 0) { su1r[uflat] = pa; su2r[uflat] = pw; }
        }
        __syncthreads();
        // Round B: u3 = A0 u2, u4 = W u1
        {
            float pb = dot32(ra, su2r + q * QPAD);
            float pc = dot32(rw, su1r + q * QPAD);
            pb += __shfl_xor(pb, 1); pb += __shfl_xor(pb, 2);
            pc += __shfl_xor(pc, 1); pc += __shfl_xor(pc, 2);
            if (q == 0) { su3r[uflat] = pb; su4r[uflat] = pc; }
        }
        __syncthreads();
        if (tid < D_SZ) {
            int f = (tid >> 5) * QPAD + (tid & 31);
            float wn = h * su1r[f] + hs * su2r[f] - c3 * (su3r[f] - su4r[f]);
            wn *= (1.0f / (float)k);     // folds to constant (unrolled)
            yacc += wn;
            svr[f] = wn;
        }
        __syncthreads();
    }

    if (tid < D_SZ) {
        out[(size_t)b * D_SZ + tid] = yacc;
    }
}

extern "C" void kernel_launch(void* const* d_in, const int* in_sizes, int n_in,
                              void* d_out, int out_size, void* d_ws, size_t ws_size,
                              hipStream_t stream) {
    const float* t0 = (const float*)d_in[0];
    const float* h  = (const float*)d_in[1];
    const float* y0 = (const float*)d_in[2];
    const float* A0 = (const float*)d_in[3];
    const float* W  = (const float*)d_in[4];
    float* out = (float*)d_out;
    magnus_kernel<<<B_SZ, 512, 0, stream>>>(t0, h, y0, A0, W, out);
}

// Round 9
// 252.235 us; speedup vs baseline: 1.1003x; 1.1003x over previous
//
#include <hip/hip_runtime.h>

#define B_SZ 1024
#define D_SZ 128
#define KTERMS 7
#define QPAD 36   // floats per quarter-segment: 32 data + 4 pad

typedef float vfloat4 __attribute__((ext_vector_type(4)));

__device__ inline float bflo(unsigned u) { return __uint_as_float(u << 16); }
__device__ inline float bfhi(unsigned u) { return __uint_as_float(u & 0xffff0000u); }

// 32-elem dot: 16 bf16-pair uints (REGISTERS) x 8 LDS float4 broadcast reads.
__device__ inline float dot32(const unsigned* rq, const float* v) {
    float a0 = 0.f, a1 = 0.f, a2 = 0.f, a3 = 0.f;
#pragma unroll
    for (int j = 0; j < 8; ++j) {
        vfloat4 vv = *(const vfloat4*)(v + 4 * j);
        a0 = fmaf(bflo(rq[2 * j]),     vv.x, a0);
        a1 = fmaf(bfhi(rq[2 * j]),     vv.y, a1);
        a2 = fmaf(bflo(rq[2 * j + 1]), vv.z, a2);
        a3 = fmaf(bfhi(rq[2 * j + 1]), vv.w, a3);
    }
    return (a0 + a1) + (a2 + a3);
}

// TWO INDEPENDENT JOBS in one heterogeneous grid (A1/A2 do NOT feed the expm):
//   J1 (stream): A1 = A0 + t1*W, A2 = A0 + t2*W, coalesced + nontemporal.
//   J2 (expm):   y = expm(Omega) y0, quarter-rows of A0,W held bf16 in regs.
// Interleave in groups of 8 so round-robin XCD dispatch gives every XCD both
// job kinds -> streaming waves and latency-chain waves co-resident per CU.
__global__ void __launch_bounds__(512, 4)
magnus_kernel(const float* __restrict__ t0p, const float* __restrict__ hp,
              const float* __restrict__ y0, const float* __restrict__ A0,
              const float* __restrict__ W, float* __restrict__ out)
{
    __shared__ __align__(16) float svr [4 * QPAD];
    __shared__ __align__(16) float su1r[4 * QPAD];
    __shared__ __align__(16) float su2r[4 * QPAD];
    __shared__ __align__(16) float su3r[4 * QPAD];
    __shared__ __align__(16) float su4r[4 * QPAD];

    const int tid   = threadIdx.x;
    const int grpid = blockIdx.x >> 3;                 // 0..255
    const int job   = grpid & 1;                        // 0 = J1 stream, 1 = J2 expm
    const int b     = ((grpid >> 1) << 3) + (blockIdx.x & 7);  // 0..1023

    const float h  = hp[0];
    const float tb = t0p[b];
    const size_t moff = (size_t)b * (D_SZ * D_SZ);

    if (job == 0) {
        // ---- J1: pure streaming, fully coalesced, nontemporal stores ----
        const float SQ3_6 = 0.28867513459481287f;  // sqrt(3)/6
        const float t1 = tb + (0.5f - SQ3_6) * h;
        const float t2 = tb + (0.5f + SQ3_6) * h;
        const float4* A0v = (const float4*)(A0 + moff);
        const float4* Wv  = (const float4*)(W + moff);
        vfloat4* o1 = (vfloat4*)(out + (size_t)B_SZ * D_SZ + moff);
        vfloat4* o2 = (vfloat4*)(out + (size_t)B_SZ * D_SZ
                                     + (size_t)B_SZ * D_SZ * D_SZ + moff);
#pragma unroll 8
        for (int it = 0; it < 8; ++it) {
            int i = it * 512 + tid;
            float4 a = A0v[i];
            float4 w = Wv[i];
            vfloat4 p1, p2;
            p1.x = fmaf(t1, w.x, a.x); p1.y = fmaf(t1, w.y, a.y);
            p1.z = fmaf(t1, w.z, a.z); p1.w = fmaf(t1, w.w, a.w);
            p2.x = fmaf(t2, w.x, a.x); p2.y = fmaf(t2, w.y, a.y);
            p2.z = fmaf(t2, w.z, a.z); p2.w = fmaf(t2, w.w, a.w);
            __builtin_nontemporal_store(p1, o1 + i);
            __builtin_nontemporal_store(p2, o2 + i);
        }
        return;
    }

    // ---- J2: expm(Omega) y0.  Thread owns quarter-row of BOTH A0,W in regs.
    // Reads are 128B/thread contiguous (lane stride 128B): line fills absorbed
    // by L1/L2 (r8 measured FETCH ~73MB, fine).  NO matrix stores here - the
    // write-amplification that sank r8 is gone (J1 owns all big stores).
    const int row = tid >> 2;     // 0..127
    const int q   = tid & 3;      // quarter 0..3
    const int fbase = row * 32 + q * 8;   // float4 index of thread's 128B chunk

    const float4* Ap = (const float4*)(A0 + moff) + fbase;
    const float4* Wp = (const float4*)(W + moff) + fbase;
    unsigned ra[16], rw[16];
#pragma unroll
    for (int it = 0; it < 8; ++it) {
        float4 a = Ap[it];
        float4 w = Wp[it];
        asm("v_cvt_pk_bf16_f32 %0, %1, %2" : "=v"(ra[2*it])   : "v"(a.x), "v"(a.y));
        asm("v_cvt_pk_bf16_f32 %0, %1, %2" : "=v"(ra[2*it+1]) : "v"(a.z), "v"(a.w));
        asm("v_cvt_pk_bf16_f32 %0, %1, %2" : "=v"(rw[2*it])   : "v"(w.x), "v"(w.y));
        asm("v_cvt_pk_bf16_f32 %0, %1, %2" : "=v"(rw[2*it+1]) : "v"(w.z), "v"(w.w));
    }

    float yacc = 0.0f;
    if (tid < D_SZ) {
        float v = y0[(size_t)b * D_SZ + tid];
        svr[(tid >> 5) * QPAD + (tid & 31)] = v;
        yacc = v;
    }
    __syncthreads();

    const float hs = h * (tb + 0.5f * h);           // h * s
    const float c3 = h * h * h * (1.0f / 12.0f);    // h^3 / 12
    const int uflat = (row >> 5) * QPAD + (row & 31);
    // KTERMS=7: ||Omega|| <~ 0.3 -> truncation ~2e-8, invisible vs bf16 noise.

#pragma unroll
    for (int k = 1; k <= KTERMS; ++k) {
        // Round A: u1 = A0 v, u2 = W v (both dots share one v-read)
        {
            const float* vq = svr + q * QPAD;
            float pa = dot32(ra, vq);
            float pw = dot32(rw, vq);
            pa += __shfl_xor(pa, 1); pa += __shfl_xor(pa, 2);
            pw += __shfl_xor(pw, 1); pw += __shfl_xor(pw, 2);
            if (q == 0) { su1r[uflat] = pa; su2r[uflat] = pw; }
        }
        __syncthreads();
        // Round B: u3 = A0 u2, u4 = W u1
        {
            float pb = dot32(ra, su2r + q * QPAD);
            float pc = dot32(rw, su1r + q * QPAD);
            pb += __shfl_xor(pb, 1); pb += __shfl_xor(pb, 2);
            pc += __shfl_xor(pc, 1); pc += __shfl_xor(pc, 2);
            if (q == 0) { su3r[uflat] = pb; su4r[uflat] = pc; }
        }
        __syncthreads();
        if (tid < D_SZ) {
            int f = (tid >> 5) * QPAD + (tid & 31);
            float wn = h * su1r[f] + hs * su2r[f] - c3 * (su3r[f] - su4r[f]);
            wn *= (1.0f / (float)k);     // folds to constant (unrolled)
            yacc += wn;
            svr[f] = wn;
        }
        __syncthreads();
    }

    if (tid < D_SZ) {
        out[(size_t)b * D_SZ + tid] = yacc;
    }
}

extern "C" void kernel_launch(void* const* d_in, const int* in_sizes, int n_in,
                              void* d_out, int out_size, void* d_ws, size_t ws_size,
                              hipStream_t stream) {
    const float* t0 = (const float*)d_in[0];
    const float* h  = (const float*)d_in[1];
    const float* y0 = (const float*)d_in[2];
    const float* A0 = (const float*)d_in[3];
    const float* W  = (const float*)d_in[4];
    float* out = (float*)d_out;
    magnus_kernel<<<2 * B_SZ, 512, 0, stream>>>(t0, h, y0, A0, W, out);
}